// Round 5
// baseline (556.752 us; speedup 1.0000x reference)
//
#include <hip/hip_runtime.h>
#include <hip/hip_cooperative_groups.h>
#include <cstddef>

namespace cg = cooperative_groups;

// HMM forward-backward posterior. Emission terms are state-independent scalars
// per (b,t); they and the batch dim cancel in the per-t state normalization,
// so gamma[b,t,i] == gamma[t,i]. Only the emission-free recursions
// A_t = A_{t-1} (x) M, B_t = M (x) B_{t+1} (log-matmul) matter.
// Round-4 lesson: 15 serial launches cost ~15 us each in launch overhead
// (~225 of 307 us). This round: ONE cooperative kernel, 11 grid.sync()s
// replace 14 launch boundaries. 256 blocks x 512 threads = 1 block/CU
// (co-residency guaranteed: ~18 KB LDS, VGPR<=256 via launch_bounds).
// Phases: 8 squarings (M^2..M^256) -> level-0 scan (15 steps, M^256) ->
// level-1 (32 chunks, M^16) -> level-2 fused gamma (256 chunks, M) ->
// broadcast 134 MB to all 64 batch slots.

constexpr int NS = 128;
constexpr int TT = 4096;
constexpr int LVL = 16;

// ws offsets (floats)
constexpr int OFF_P0   = 0;
constexpr int OFF_P1   = 16384;
constexpr int OFF_P16  = 32768;   // M^16 (log)
constexpr int OFF_P256 = 49152;   // M^256 (log)
constexpr int OFF_AB1  = 65536;   // [16][128] alpha boundaries (t=256c)
constexpr int OFF_BB1  = 67584;   // [16][128] beta  boundaries
constexpr int OFF_AB2  = 69632;   // [256][128] alpha boundaries (t=16d)
constexpr int OFF_BB2  = 102400;  // [256][128]
constexpr int OFF_G    = 135168;  // gamma plane [4096][128]
// total 659,456 floats ~ 2.5 MiB

__device__ __forceinline__ float wredmax(float v) {
#pragma unroll
  for (int off = 32; off; off >>= 1) v = fmaxf(v, __shfl_xor(v, off, 64));
  return v;
}
__device__ __forceinline__ float wredsum(float v) {
#pragma unroll
  for (int off = 32; off; off >>= 1) v += __shfl_xor(v, off, 64);
  return v;
}

__global__ __launch_bounds__(512, 2) void hmm_mega(const float* __restrict__ pi,
                                                   const float* __restrict__ Tm,
                                                   float* __restrict__ ws,
                                                   float* __restrict__ out) {
  cg::grid_group grid = cg::this_grid();
  __shared__ __align__(16) float Ga[LVL][NS];
  __shared__ __align__(16) float Gb[LVL][NS];
  __shared__ __align__(16) float wsA[NS];
  __shared__ __align__(16) float wsB[NS];
  __shared__ float red[2];
  const int tid = threadIdx.x;
  const int blk = blockIdx.x;

  float* P0 = ws + OFF_P0;
  float* P1 = ws + OFF_P1;
  float* P16 = ws + OFF_P16;
  float* P256 = ws + OFF_P256;

  // ---------------- phase 1: squaring chain (8 stages) ----------------
  // block = output row, threads 0..127 = columns; lane i holds
  // exp(src[:,i]-colmax_i) in 128 VGPRs; row weights broadcast via LDS.
  {
    const float* sq_src[8] = {Tm, P0, P1, P0, P16, P1, P0, P1};
    float*       sq_dst[8] = {P0, P1, P0, P16, P1, P0, P1, P256};
    for (int s = 0; s < 8; ++s) {
      const float* src = sq_src[s];
      float* dst = sq_dst[s];
      bool act = (blk < NS) && (tid < NS);
      float Ereg[NS];
      float c = -1e30f, xr = 0.f;
      if (act) {
#pragma unroll
        for (int j = 0; j < NS; ++j) { float v = src[j * NS + tid]; Ereg[j] = v; c = fmaxf(c, v); }
#pragma unroll
        for (int j = 0; j < NS; ++j) Ereg[j] = __expf(Ereg[j] - c);
        xr = src[blk * NS + tid];
      }
      float m = wredmax(act ? xr : -1e30f);
      if (act && (tid & 63) == 0) red[tid >> 6] = m;
      __syncthreads();
      float rm = fmaxf(red[0], red[1]);
      if (act) wsA[tid] = __expf(xr - rm);
      __syncthreads();
      if (act) {
        float acc = 0.f;
        const float4* w4 = (const float4*)wsA;
#pragma unroll
        for (int j = 0; j < 32; ++j) {
          float4 wv = w4[j];
          acc += wv.x * Ereg[4 * j] + wv.y * Ereg[4 * j + 1] +
                 wv.z * Ereg[4 * j + 2] + wv.w * Ereg[4 * j + 3];
        }
        dst[blk * NS + tid] = __logf(fmaxf(acc, 1e-37f)) + rm + c;
      }
      __syncthreads();   // wsA/red reuse next stage
      grid.sync();
    }
  }

  // ---------------- boundary scan helper (single side per block) -------
  // alpha layout: Ereg[j]=exp(logmat[j][lane]-colmax)  (coalesced column load)
  // beta  layout: Ereg[k]=exp(logmat[lane][k]-rowmax)  (lane-contiguous float4 row)
  auto scan_side = [&](const float* logmat, const float* inA, const float* inB,
                       float* outA, float* outB, int nch) {
    bool act = (blk < 2 * nch) && (tid < NS);
    bool isA = blk < nch;
    int c = isA ? blk : blk - nch;
    int lane = tid;
    float Ereg[NS];
    float cm = 0.f;
    if (act) {
      float mx = -1e30f;
      if (isA) {
#pragma unroll
        for (int j = 0; j < NS; ++j) { float v = logmat[j * NS + lane]; Ereg[j] = v; mx = fmaxf(mx, v); }
      } else {
        const float4* row = (const float4*)(logmat + lane * NS);
#pragma unroll
        for (int k = 0; k < 32; ++k) {
          float4 v = row[k];
          Ereg[4 * k] = v.x; Ereg[4 * k + 1] = v.y; Ereg[4 * k + 2] = v.z; Ereg[4 * k + 3] = v.w;
          mx = fmaxf(mx, fmaxf(fmaxf(v.x, v.y), fmaxf(v.z, v.w)));
        }
      }
#pragma unroll
      for (int j = 0; j < NS; ++j) Ereg[j] = __expf(Ereg[j] - mx);
      cm = mx;
    }
    float x = 0.f;
    float* outp = nullptr;
    if (act) {
      x = isA ? (inA ? inA[c * NS + lane] : pi[lane])
              : (inB ? inB[c * NS + lane] : 0.f);
      outp = (isA ? outA : outB) + (size_t)c * LVL * NS;
      outp[(isA ? 0 : LVL - 1) * NS + lane] = x;
    }
    for (int it = 1; it < LVL; ++it) {
      if (act) wsA[lane] = x;
      __syncthreads();
      if (act) wsB[lane] = __expf(x - wsA[0]);
      __syncthreads();
      if (act) {
        float acc = 0.f;
        const float4* w4 = (const float4*)wsB;
#pragma unroll
        for (int j = 0; j < 32; ++j) {
          float4 wv = w4[j];
          acc += wv.x * Ereg[4 * j] + wv.y * Ereg[4 * j + 1] +
                 wv.z * Ereg[4 * j + 2] + wv.w * Ereg[4 * j + 3];
        }
        x = __logf(fmaxf(acc, 1e-37f)) + cm;
        outp[(isA ? it : LVL - 1 - it) * NS + lane] = x;
      }
      __syncthreads();
    }
  };

  // ---------------- phase 2: level-0 (M^256, 1 chunk each side) --------
  scan_side(P256, nullptr, nullptr, ws + OFF_AB1, ws + OFF_BB1, 1);
  grid.sync();
  // ---------------- phase 3: level-1 (M^16, 16 chunks each side) -------
  scan_side(P16, ws + OFF_AB1, ws + OFF_BB1, ws + OFF_AB2, ws + OFF_BB2, 16);
  grid.sync();

  // ---------------- phase 4: level-2 fused gamma (M, 256 chunks) -------
  {
    bool act = tid < 256;
    bool isA = tid < NS;
    int lane = tid & (NS - 1);
    int c = blk;
    float Ereg[NS];
    float cm = 0.f;
    if (act) {
      float mx = -1e30f;
      if (isA) {
#pragma unroll
        for (int j = 0; j < NS; ++j) { float v = Tm[j * NS + lane]; Ereg[j] = v; mx = fmaxf(mx, v); }
      } else {
        const float4* row = (const float4*)(Tm + lane * NS);
#pragma unroll
        for (int k = 0; k < 32; ++k) {
          float4 v = row[k];
          Ereg[4 * k] = v.x; Ereg[4 * k + 1] = v.y; Ereg[4 * k + 2] = v.z; Ereg[4 * k + 3] = v.w;
          mx = fmaxf(mx, fmaxf(fmaxf(v.x, v.y), fmaxf(v.z, v.w)));
        }
      }
#pragma unroll
      for (int j = 0; j < NS; ++j) Ereg[j] = __expf(Ereg[j] - mx);
      cm = mx;
    }
    float x = 0.f;
    if (act) {
      if (isA) { x = ws[OFF_AB2 + c * NS + lane]; Ga[0][lane] = x; }
      else     { x = ws[OFF_BB2 + c * NS + lane]; Gb[LVL - 1][lane] = x; }
    }
    __syncthreads();
    for (int it = 1; it < LVL; ++it) {
      int sprev = isA ? it - 1 : LVL - it;
      int scur  = isA ? it     : LVL - 1 - it;
      if (act) {
        float ref = isA ? Ga[sprev][0] : Gb[sprev][0];
        (isA ? wsA : wsB)[lane] = __expf(x - ref);
      }
      __syncthreads();
      if (act) {
        const float4* w4 = (const float4*)(isA ? wsA : wsB);
        float acc = 0.f;
#pragma unroll
        for (int j = 0; j < 32; ++j) {
          float4 wv = w4[j];
          acc += wv.x * Ereg[4 * j] + wv.y * Ereg[4 * j + 1] +
                 wv.z * Ereg[4 * j + 2] + wv.w * Ereg[4 * j + 3];
        }
        x = __logf(fmaxf(acc, 1e-37f)) + cm;
        if (isA) Ga[scur][lane] = x; else Gb[scur][lane] = x;
      }
      __syncthreads();
    }
    // normalize: wave w handles rows 4w..4w+3 (lane l covers i=l, i=l+64)
    int w = tid >> 6, l = tid & 63;
    if (act) {
#pragma unroll
      for (int r = 0; r < 4; ++r) {
        int s = w * 4 + r;
        float a0 = Ga[s][l] + Gb[s][l];
        float a1 = Ga[s][l + 64] + Gb[s][l + 64];
        float mx = wredmax(fmaxf(a0, a1));
        float p = __expf(a0 - mx) + __expf(a1 - mx);
        float sm = wredsum(p);
        float lse = __logf(sm) + mx;
        Ga[s][l] = a0 - lse;
        Ga[s][l + 64] = a1 - lse;
      }
    }
    __syncthreads();
    if (act) {
      const float4* G4 = (const float4*)Ga;
      float4* plane4 = (float4*)(ws + OFF_G);
      plane4[(size_t)c * 512 + tid] = G4[tid];
      plane4[(size_t)c * 512 + tid + 256] = G4[tid + 256];
    }
  }
  grid.sync();

  // ---------------- phase 5: broadcast plane -> 64 batch slots ---------
  // out[b][t][i] flat float4 idx = b*131072 + (t*128+i)/4; plane is 2^17
  // float4s so src idx = dst idx & 131071. 256 blocks x 512 thr x 64 iters.
  {
    const float4* plane4 = (const float4*)(ws + OFF_G);
    float4* o4 = (float4*)out;
    size_t base = (size_t)blk * 32768;
#pragma unroll 4
    for (int k = 0; k < 64; ++k) {
      size_t idx = base + (size_t)k * 512 + tid;
      o4[idx] = plane4[idx & 131071];
    }
  }
}

extern "C" void kernel_launch(void* const* d_in, const int* in_sizes, int n_in,
                              void* d_out, int out_size, void* d_ws, size_t ws_size,
                              hipStream_t stream) {
  (void)in_sizes; (void)n_in; (void)out_size; (void)ws_size;
  const float* pi = (const float*)d_in[1];
  const float* Tm = (const float*)d_in[2];
  float* ws = (float*)d_ws;
  float* out = (float*)d_out;

  void* args[] = {(void*)&pi, (void*)&Tm, (void*)&ws, (void*)&out};
  hipLaunchCooperativeKernel((void*)hmm_mega, dim3(256), dim3(512), args, 0, stream);
}

// Round 7
// 527.789 us; speedup vs baseline: 1.0549x; 1.0549x over previous
//
#include <hip/hip_runtime.h>
#include <hip/hip_cooperative_groups.h>
#include <cstddef>

namespace cg = cooperative_groups;

// HMM forward-backward posterior. Emission terms are state-independent scalars
// per (b,t); they and the batch dim cancel in the per-t state normalization,
// so gamma[b,t,i] == gamma[t,i]. Only the emission-free recursions
// A_t = A_{t-1} (x) M, B_t = M (x) B_{t+1} (log-matmul) matter.
// ONE cooperative kernel (round-4: ~15us per serial launch). Round-5 lesson:
// launch_bounds(512,2) spilled Ereg[128] -> scratch (438us). Round-6 lesson:
// __syncthreads() inside a tid-dependent guard = divergent barrier = UB
// (corrupted results). This round: 256 blocks x 256 threads,
// launch_bounds(256,1) for the full 512-VGPR budget, and EVERY barrier is
// executed unconditionally by all threads of the block.
// Phases: 8 squarings (M^2..M^256) -> level-0 scan (M^256) -> level-1 (M^16)
// -> level-2 fused gamma (M) -> broadcast 134MB.

constexpr int NS = 128;
constexpr int LVL = 16;

// ws offsets (floats)
constexpr int OFF_P0   = 0;
constexpr int OFF_P1   = 16384;
constexpr int OFF_P16  = 32768;   // M^16 (log)
constexpr int OFF_P256 = 49152;   // M^256 (log)
constexpr int OFF_AB1  = 65536;   // [16][128] alpha boundaries (t=256c)
constexpr int OFF_BB1  = 67584;   // [16][128] beta  boundaries (t=256c+255)
constexpr int OFF_AB2  = 69632;   // [256][128] alpha boundaries (t=16d)
constexpr int OFF_BB2  = 102400;  // [256][128] beta boundaries (t=16d+15)
constexpr int OFF_G    = 135168;  // gamma plane [4096][128]
// total 659,456 floats ~ 2.5 MiB

__device__ __forceinline__ float wredmax(float v) {
#pragma unroll
  for (int off = 32; off; off >>= 1) v = fmaxf(v, __shfl_xor(v, off, 64));
  return v;
}
__device__ __forceinline__ float wredsum(float v) {
#pragma unroll
  for (int off = 32; off; off >>= 1) v += __shfl_xor(v, off, 64);
  return v;
}

__global__ __launch_bounds__(256, 1) void hmm_mega(const float* __restrict__ pi,
                                                   const float* __restrict__ Tm,
                                                   float* __restrict__ ws,
                                                   float* __restrict__ out) {
  cg::grid_group grid = cg::this_grid();
  __shared__ __align__(16) float Ga[LVL][NS];
  __shared__ __align__(16) float Gb[LVL][NS];
  __shared__ __align__(16) float wsA[NS];
  __shared__ __align__(16) float wsB[NS];
  __shared__ float red[2];
  const int tid = threadIdx.x;
  const int blk = blockIdx.x;

  float* P0 = ws + OFF_P0;
  float* P1 = ws + OFF_P1;
  float* P16 = ws + OFF_P16;
  float* P256 = ws + OFF_P256;

  // ---------------- phase 1: squaring chain (8 stages) ----------------
  // block = output row (blk<128), threads 0..127 = columns; lane i holds
  // exp(src[:,i]-colmax_i) in 128 VGPRs; row weights broadcast via LDS.
  // Barriers unconditional: threads 128..255 idle through them.
  {
    const float* sq_src[8] = {Tm, P0, P1, P0, P16, P1, P0, P1};
    float*       sq_dst[8] = {P0, P1, P0, P16, P1, P0, P1, P256};
#pragma unroll 1
    for (int s = 0; s < 8; ++s) {
      const float* src = sq_src[s];
      float* dst = sq_dst[s];
      bool act = (blk < NS) && (tid < NS);
      float Ereg[NS];
      float c = -1e30f, xr = -1e30f;
      if (act) {
#pragma unroll
        for (int j = 0; j < NS; ++j) { float v = src[j * NS + tid]; Ereg[j] = v; c = fmaxf(c, v); }
#pragma unroll
        for (int j = 0; j < NS; ++j) Ereg[j] = __expf(Ereg[j] - c);
        xr = src[blk * NS + tid];
      }
      float m = wredmax(xr);
      if (act && (tid & 63) == 0) red[tid >> 6] = m;
      __syncthreads();
      float rm = fmaxf(red[0], red[1]);
      if (act) wsA[tid] = __expf(xr - rm);
      __syncthreads();
      if (act) {
        float acc = 0.f;
        const float4* w4 = (const float4*)wsA;
#pragma unroll
        for (int j = 0; j < 32; ++j) {
          float4 wv = w4[j];
          acc += wv.x * Ereg[4 * j] + wv.y * Ereg[4 * j + 1] +
                 wv.z * Ereg[4 * j + 2] + wv.w * Ereg[4 * j + 3];
        }
        dst[blk * NS + tid] = __logf(fmaxf(acc, 1e-37f)) + rm + c;
      }
      __syncthreads();   // wsA/red reused next stage
      grid.sync();
    }
  }

  // ---------------- boundary scan helper --------------------------------
  // alpha: Ereg[j]=exp(logmat[j][lane]-colmax_lane)  (coalesced column load)
  // beta : Ereg[k]=exp(logmat[lane][k]-rowmax_lane)  (float4 row load, L2)
  // All barriers unconditional.
  auto scan_side = [&](const float* logmat, const float* inA, const float* inB,
                       float* outA, float* outB, int nch) {
    bool act = (blk < 2 * nch) && (tid < NS);
    bool isA = blk < nch;
    int c = isA ? blk : blk - nch;
    int lane = tid;
    float Ereg[NS];
    float cm = 0.f;
    if (act) {
      float mx = -1e30f;
      if (isA) {
#pragma unroll
        for (int j = 0; j < NS; ++j) { float v = logmat[j * NS + lane]; Ereg[j] = v; mx = fmaxf(mx, v); }
      } else {
        const float4* row = (const float4*)(logmat + lane * NS);
#pragma unroll
        for (int k = 0; k < 32; ++k) {
          float4 v = row[k];
          Ereg[4 * k] = v.x; Ereg[4 * k + 1] = v.y; Ereg[4 * k + 2] = v.z; Ereg[4 * k + 3] = v.w;
          mx = fmaxf(mx, fmaxf(fmaxf(v.x, v.y), fmaxf(v.z, v.w)));
        }
      }
#pragma unroll
      for (int j = 0; j < NS; ++j) Ereg[j] = __expf(Ereg[j] - mx);
      cm = mx;
    }
    float x = 0.f;
    float* outp = nullptr;
    if (act) {
      x = isA ? (inA ? inA[c * NS + lane] : pi[lane])
              : (inB ? inB[c * NS + lane] : 0.f);
      outp = (isA ? outA : outB) + (size_t)c * LVL * NS;
      outp[(isA ? 0 : LVL - 1) * NS + lane] = x;
    }
#pragma unroll 1
    for (int it = 1; it < LVL; ++it) {
      if (act) wsA[lane] = x;
      __syncthreads();
      if (act) wsB[lane] = __expf(x - wsA[0]);
      __syncthreads();
      if (act) {
        float acc = 0.f;
        const float4* w4 = (const float4*)wsB;
#pragma unroll
        for (int j = 0; j < 32; ++j) {
          float4 wv = w4[j];
          acc += wv.x * Ereg[4 * j] + wv.y * Ereg[4 * j + 1] +
                 wv.z * Ereg[4 * j + 2] + wv.w * Ereg[4 * j + 3];
        }
        x = __logf(fmaxf(acc, 1e-37f)) + cm;
        outp[(isA ? it : LVL - 1 - it) * NS + lane] = x;
      }
      __syncthreads();
    }
  };

  // ---------------- phase 2: level-0 (M^256, 1 chunk/side) -------------
  scan_side(P256, nullptr, nullptr, ws + OFF_AB1, ws + OFF_BB1, 1);
  grid.sync();
  // ---------------- phase 3: level-1 (M^16, 16 chunks/side) ------------
  scan_side(P16, ws + OFF_AB1, ws + OFF_BB1, ws + OFF_AB2, ws + OFF_BB2, 16);
  grid.sync();

  // ---------------- phase 4: level-2 fused gamma (M, 256 chunks) -------
  // All 256 threads active: tid<128 alpha chain, tid>=128 beta chain.
  {
    bool isA = tid < NS;
    int lane = tid & (NS - 1);
    int c = blk;
    float Ereg[NS];
    float mx = -1e30f;
    if (isA) {
#pragma unroll
      for (int j = 0; j < NS; ++j) { float v = Tm[j * NS + lane]; Ereg[j] = v; mx = fmaxf(mx, v); }
    } else {
      const float4* row = (const float4*)(Tm + lane * NS);
#pragma unroll
      for (int k = 0; k < 32; ++k) {
        float4 v = row[k];
        Ereg[4 * k] = v.x; Ereg[4 * k + 1] = v.y; Ereg[4 * k + 2] = v.z; Ereg[4 * k + 3] = v.w;
        mx = fmaxf(mx, fmaxf(fmaxf(v.x, v.y), fmaxf(v.z, v.w)));
      }
    }
#pragma unroll
    for (int j = 0; j < NS; ++j) Ereg[j] = __expf(Ereg[j] - mx);
    float cm = mx;
    float x;
    if (isA) { x = ws[OFF_AB2 + c * NS + lane]; Ga[0][lane] = x; }
    else     { x = ws[OFF_BB2 + c * NS + lane]; Gb[LVL - 1][lane] = x; }
    __syncthreads();
#pragma unroll 1
    for (int it = 1; it < LVL; ++it) {
      int sprev = isA ? it - 1 : LVL - it;
      int scur  = isA ? it     : LVL - 1 - it;
      float ref = isA ? Ga[sprev][0] : Gb[sprev][0];
      (isA ? wsA : wsB)[lane] = __expf(x - ref);
      __syncthreads();
      const float4* w4 = (const float4*)(isA ? wsA : wsB);
      float acc = 0.f;
#pragma unroll
      for (int j = 0; j < 32; ++j) {
        float4 wv = w4[j];
        acc += wv.x * Ereg[4 * j] + wv.y * Ereg[4 * j + 1] +
               wv.z * Ereg[4 * j + 2] + wv.w * Ereg[4 * j + 3];
      }
      x = __logf(fmaxf(acc, 1e-37f)) + cm;
      if (isA) Ga[scur][lane] = x; else Gb[scur][lane] = x;
      __syncthreads();
    }
    // normalize: wave w handles rows 4w..4w+3 (lane l covers i=l, i=l+64)
    int w = tid >> 6, l = tid & 63;
#pragma unroll
    for (int r = 0; r < 4; ++r) {
      int s = w * 4 + r;
      float a0 = Ga[s][l] + Gb[s][l];
      float a1 = Ga[s][l + 64] + Gb[s][l + 64];
      float m2 = wredmax(fmaxf(a0, a1));
      float p = __expf(a0 - m2) + __expf(a1 - m2);
      float sm = wredsum(p);
      float lse = __logf(sm) + m2;
      Ga[s][l] = a0 - lse;
      Ga[s][l + 64] = a1 - lse;
    }
    __syncthreads();
    const float4* G4 = (const float4*)Ga;
    float4* plane4 = (float4*)(ws + OFF_G);
    plane4[(size_t)c * 512 + tid] = G4[tid];
    plane4[(size_t)c * 512 + tid + 256] = G4[tid + 256];
  }
  grid.sync();

  // ---------------- phase 5: broadcast plane -> 64 batch slots ---------
  // out is 8,388,608 float4s; plane is 131,072 float4s (2MB, L2-resident).
  // 256 blocks x 256 thr x 128 float4 stores, fully coalesced streaming.
  {
    const float4* plane4 = (const float4*)(ws + OFF_G);
    float4* o4 = (float4*)out;
    size_t base = (size_t)blk * 32768;
#pragma unroll 8
    for (int k = 0; k < 128; ++k) {
      size_t idx = base + (size_t)k * 256 + tid;
      o4[idx] = plane4[idx & 131071];
    }
  }
}

extern "C" void kernel_launch(void* const* d_in, const int* in_sizes, int n_in,
                              void* d_out, int out_size, void* d_ws, size_t ws_size,
                              hipStream_t stream) {
  (void)in_sizes; (void)n_in; (void)out_size; (void)ws_size;
  const float* pi = (const float*)d_in[1];
  const float* Tm = (const float*)d_in[2];
  float* ws = (float*)d_ws;
  float* out = (float*)d_out;

  void* args[] = {(void*)&pi, (void*)&Tm, (void*)&ws, (void*)&out};
  hipLaunchCooperativeKernel((void*)hmm_mega, dim3(256), dim3(256), args, 0, stream);
}